// Round 7
// baseline (249.906 us; speedup 1.0000x reference)
//
#include <hip/hip_runtime.h>
#include <math.h>

// Problem constants (B=2, H=W=48, C=E=256, NH=8, GH=1)
#define NTOK 2304              // H*W
#define NS   4608              // B*NTOK
#define CH   256               // C == E == E*GH

using bf16x8 = __attribute__((ext_vector_type(8))) short;
using f32x4  = __attribute__((ext_vector_type(4))) float;

#define EXP2F(x) __builtin_amdgcn_exp2f(x)

__device__ __forceinline__ unsigned short f2bf(float x) {
    unsigned int u = __float_as_uint(x);
    u = (u + 0x7fffu + ((u >> 16) & 1u)) >> 16;   // RNE
    return (unsigned short)u;
}

// ---------------- block LN reduce: wave shfl + 1 barrier ----------------
__device__ __forceinline__ void red2(float& a, float& b, float* s1, float* s2) {
    #pragma unroll
    for (int off = 32; off; off >>= 1) {
        a += __shfl_xor(a, off, 64);
        b += __shfl_xor(b, off, 64);
    }
    int t = threadIdx.x;
    if ((t & 63) == 0) { s1[t >> 6] = a; s2[t >> 6] = b; }
    __syncthreads();
    a = s1[0] + s1[1] + s1[2] + s1[3];
    b = s2[0] + s2[1] + s2[2] + s2[3];
}

// LN over channel dim while transposing [B,C,N] -> [Ns, C]
__global__ __launch_bounds__(256) void k_ln_tok(const float* __restrict__ x,
    const float* __restrict__ g, const float* __restrict__ be, float* __restrict__ out)
{
    int row = blockIdx.x;              // b*NTOK + n
    int b = row / NTOK, n = row - b * NTOK;
    int c = threadIdx.x;
    float v = x[((size_t)b * CH + c) * NTOK + n];
    __shared__ float s1[4], s2[4];
    float a = v, q = v * v;
    red2(a, q, s1, s2);
    float mu = a * (1.f / CH);
    float var = q * (1.f / CH) - mu * mu;
    float r = rsqrtf(var + 1e-5f);
    out[(size_t)row * CH + c] = (v - mu) * r * g[c] + be[c];
}

__global__ __launch_bounds__(256) void k_ln(const float* __restrict__ in,
    const float* __restrict__ g, const float* __restrict__ be, float* __restrict__ out)
{
    int row = blockIdx.x;
    int c = threadIdx.x;
    float v = in[(size_t)row * CH + c];
    __shared__ float s1[4], s2[4];
    float a = v, q = v * v;
    red2(a, q, s1, s2);
    float mu = a * (1.f / CH);
    float var = q * (1.f / CH) - mu * mu;
    float r = rsqrtf(var + 1e-5f);
    out[(size_t)row * CH + c] = (v - mu) * r * g[c] + be[c];
}

// final LN + transpose to [B, E, H*W]
__global__ __launch_bounds__(256) void k_ln_out(const float* __restrict__ in,
    const float* __restrict__ g, const float* __restrict__ be, float* __restrict__ out)
{
    int row = blockIdx.x;
    int b = row / NTOK, n = row - b * NTOK;
    int c = threadIdx.x;
    float v = in[(size_t)row * CH + c];
    __shared__ float s1[4], s2[4];
    float a = v, q = v * v;
    red2(a, q, s1, s2);
    float mu = a * (1.f / CH);
    float var = q * (1.f / CH) - mu * mu;
    float r = rsqrtf(var + 1e-5f);
    float val = (v - mu) * r * g[c] + be[c];
    out[((size_t)b * CH + c) * NTOK + n] = val;
}

// ---------------- weight prep: fp32 W[k][n] -> bf16 Wt[n][k], 9 matrices ----------------
__global__ __launch_bounds__(256) void k_wprep(
    const float* __restrict__ w0, const float* __restrict__ w1,
    const float* __restrict__ w2, const float* __restrict__ w3,
    const float* __restrict__ w4, const float* __restrict__ w5,
    const float* __restrict__ w6, const float* __restrict__ w7,
    const float* __restrict__ w8, unsigned short* __restrict__ wt)
{
    const float* W;
    switch (blockIdx.z) {
        case 0: W = w0; break; case 1: W = w1; break; case 2: W = w2; break;
        case 3: W = w3; break; case 4: W = w4; break; case 5: W = w5; break;
        case 6: W = w6; break; case 7: W = w7; break; default: W = w8; break;
    }
    unsigned short* out = wt + (size_t)blockIdx.z * 65536;
    __shared__ float fs[32][33];
    int tid = threadIdx.x;
    int bk = blockIdx.x * 32, bn = blockIdx.y * 32;
    int k = tid >> 3, n4 = (tid & 7) * 4;
    float4 v = *(const float4*)&W[(size_t)(bk + k) * 256 + bn + n4];
    fs[k][n4] = v.x; fs[k][n4 + 1] = v.y; fs[k][n4 + 2] = v.z; fs[k][n4 + 3] = v.w;
    __syncthreads();
    int n = tid >> 3, k4 = (tid & 7) * 4;
    ushort4 o;
    o.x = f2bf(fs[k4 + 0][n]); o.y = f2bf(fs[k4 + 1][n]);
    o.z = f2bf(fs[k4 + 2][n]); o.w = f2bf(fs[k4 + 3][n]);
    *(ushort4*)&out[(size_t)(bn + n) * 256 + bk + k4] = o;
}

// ---------------- MFMA GEMM: out = act(A[M,256] @ W + bias (+resid)) -> fp32 ----------------
// A fp32 row-major; Wt bf16 [n][k]. Tile 64(M)x32(N), 4 waves each 16x32.
template<int ACT>
__global__ __launch_bounds__(256) void k_gemm_mfma(const float* __restrict__ A,
    const unsigned short* __restrict__ Wt, const float* __restrict__ bias,
    const float* __restrict__ resid, float* __restrict__ outf)
{
    __shared__ unsigned short As[64][40];
    int tid = threadIdx.x;
    int w = tid >> 6, l = tid & 63;
    int l15 = l & 15, hi = l >> 4;
    int bm = blockIdx.x * 64, bn = blockIdx.y * 32;

    f32x4 acc0 = {0.f, 0.f, 0.f, 0.f};
    f32x4 acc1 = {0.f, 0.f, 0.f, 0.f};
    int r0 = tid >> 3, kq = (tid & 7) * 4;

    for (int kk = 0; kk < 256; kk += 32) {
        float4 a0 = *(const float4*)&A[(size_t)(bm + r0) * 256 + kk + kq];
        float4 a1 = *(const float4*)&A[(size_t)(bm + r0 + 32) * 256 + kk + kq];
        ushort4 u0, u1;
        u0.x = f2bf(a0.x); u0.y = f2bf(a0.y); u0.z = f2bf(a0.z); u0.w = f2bf(a0.w);
        u1.x = f2bf(a1.x); u1.y = f2bf(a1.y); u1.z = f2bf(a1.z); u1.w = f2bf(a1.w);
        *(ushort4*)&As[r0][kq] = u0;
        *(ushort4*)&As[r0 + 32][kq] = u1;
        __syncthreads();
        bf16x8 af = *(const bf16x8*)&As[w * 16 + l15][hi * 8];
        bf16x8 b0 = *(const bf16x8*)&Wt[(size_t)(bn + l15) * 256 + kk + hi * 8];
        bf16x8 b1 = *(const bf16x8*)&Wt[(size_t)(bn + 16 + l15) * 256 + kk + hi * 8];
        acc0 = __builtin_amdgcn_mfma_f32_16x16x32_bf16(af, b0, acc0, 0, 0, 0);
        acc1 = __builtin_amdgcn_mfma_f32_16x16x32_bf16(af, b1, acc1, 0, 0, 0);
        __syncthreads();
    }

    #pragma unroll
    for (int j = 0; j < 2; j++) {
        #pragma unroll
        for (int r = 0; r < 4; r++) {
            float vv = (j == 0) ? acc0[r] : acc1[r];
            int gcol = bn + j * 16 + l15;
            int grow = bm + w * 16 + hi * 4 + r;
            if (bias) vv += bias[gcol];
            if (resid) vv += resid[(size_t)grow * 256 + gcol];
            if (ACT == 1) vv = 0.5f * vv * (1.f + erff(vv * 0.70710678118654752f));
            outf[(size_t)grow * 256 + gcol] = vv;
        }
    }
}

// ---------------- fused QKV GEMM: z=0 -> qb (scaled), z=1 -> kb, z=2 -> vt ----------------
__global__ __launch_bounds__(256) void k_gemm_qkv(const float* __restrict__ A,
    const unsigned short* __restrict__ Wt3,
    const float* __restrict__ bq, const float* __restrict__ bk2, const float* __restrict__ bv,
    unsigned short* __restrict__ qb, unsigned short* __restrict__ kb,
    unsigned short* __restrict__ vt, float qscale)
{
    int z = blockIdx.z;
    const unsigned short* Wt = Wt3 + (size_t)z * 65536;
    const float* bias = (z == 0) ? bq : (z == 1) ? bk2 : bv;

    __shared__ unsigned short As[64][40];
    int tid = threadIdx.x;
    int w = tid >> 6, l = tid & 63;
    int l15 = l & 15, hi = l >> 4;
    int bm = blockIdx.x * 64, bn = blockIdx.y * 32;

    f32x4 acc0 = {0.f, 0.f, 0.f, 0.f};
    f32x4 acc1 = {0.f, 0.f, 0.f, 0.f};
    int r0 = tid >> 3, kq = (tid & 7) * 4;

    for (int kk = 0; kk < 256; kk += 32) {
        float4 a0 = *(const float4*)&A[(size_t)(bm + r0) * 256 + kk + kq];
        float4 a1 = *(const float4*)&A[(size_t)(bm + r0 + 32) * 256 + kk + kq];
        ushort4 u0, u1;
        u0.x = f2bf(a0.x); u0.y = f2bf(a0.y); u0.z = f2bf(a0.z); u0.w = f2bf(a0.w);
        u1.x = f2bf(a1.x); u1.y = f2bf(a1.y); u1.z = f2bf(a1.z); u1.w = f2bf(a1.w);
        *(ushort4*)&As[r0][kq] = u0;
        *(ushort4*)&As[r0 + 32][kq] = u1;
        __syncthreads();
        bf16x8 af = *(const bf16x8*)&As[w * 16 + l15][hi * 8];
        bf16x8 b0 = *(const bf16x8*)&Wt[(size_t)(bn + l15) * 256 + kk + hi * 8];
        bf16x8 b1 = *(const bf16x8*)&Wt[(size_t)(bn + 16 + l15) * 256 + kk + hi * 8];
        acc0 = __builtin_amdgcn_mfma_f32_16x16x32_bf16(af, b0, acc0, 0, 0, 0);
        acc1 = __builtin_amdgcn_mfma_f32_16x16x32_bf16(af, b1, acc1, 0, 0, 0);
        __syncthreads();
    }

    float scale = (z == 0) ? qscale : 1.f;
    unsigned short* outqk = (z == 0) ? qb : kb;
    #pragma unroll
    for (int j = 0; j < 2; j++) {
        #pragma unroll
        for (int r = 0; r < 4; r++) {
            float vv = ((j == 0) ? acc0[r] : acc1[r]) ;
            int gcol = bn + j * 16 + l15;
            int grow = bm + w * 16 + hi * 4 + r;
            vv += bias[gcol];
            int b = grow >= NTOK;
            int tok = grow - b * NTOK;
            int h = gcol >> 5, d = gcol & 31;
            if (z < 2)
                outqk[(((size_t)(b * 8 + h)) * NTOK + tok) * 32 + d] = f2bf(vv * scale);
            else
                vt[((size_t)(b * 8 + h) * 32 + d) * NTOK + tok] = f2bf(vv);
        }
    }
}

// ---------------- MFMA flash attention (LDS-free hot loop) ----------------
// block: 16 queries, 4 waves split the 2304 keys (576 each).
// q pre-scaled by (1/sqrt(dh))*log2(e) -> exp2 domain.
// Virtual-k permutation: the swapped-QK^T C-layout leaves lane (q=l15,hi)
// holding P for keys {4hi+r, 16+4hi+r}; feed those 8 values directly as the
// PV A-fragment and assemble the matching V B-fragment from vt at the same
// permuted offsets (two 8B loads per d-block). No LDS in the loop.
__global__ __launch_bounds__(256) void k_attn_mfma(
    const unsigned short* __restrict__ qb, const unsigned short* __restrict__ kb,
    const unsigned short* __restrict__ vt, float* __restrict__ O)
{
    int bh = blockIdx.y; int b = bh >> 3, h = bh & 7;
    int tid = threadIdx.x;
    int w = tid >> 6, l = tid & 63;
    int l15 = l & 15, hi = l >> 4;
    int q0 = blockIdx.x * 16;

    bf16x8 qf = *(const bf16x8*)(qb + ((size_t)bh * NTOK + q0 + l15) * 32 + hi * 8);

    f32x4 cv0 = {0.f, 0.f, 0.f, 0.f};   // O[q=4hi+r][d=l15]
    f32x4 cv1 = {0.f, 0.f, 0.f, 0.f};   // O[q=4hi+r][d=16+l15]
    float mrun = -1e30f, lsum = 0.f;

    const unsigned short* kbh = kb + (size_t)bh * NTOK * 32;
    const unsigned short* vbh = vt + (size_t)bh * 32 * NTOK;
    const unsigned short* vrow0 = vbh + (size_t)l15 * NTOK;        // d = l15
    const unsigned short* vrow1 = vbh + (size_t)(16 + l15) * NTOK; // d = 16+l15
    int kstart = w * (NTOK / 4);

    for (int kt = 0; kt < NTOK / 4; kt += 32) {
        int kbase = kstart + kt;
        bf16x8 kf0 = *(const bf16x8*)(kbh + (size_t)(kbase + l15) * 32 + hi * 8);
        bf16x8 kf1 = *(const bf16x8*)(kbh + (size_t)(kbase + 16 + l15) * 32 + hi * 8);
        f32x4 z = {0.f, 0.f, 0.f, 0.f};
        f32x4 s0 = __builtin_amdgcn_mfma_f32_16x16x32_bf16(kf0, qf, z, 0, 0, 0);
        f32x4 s1 = __builtin_amdgcn_mfma_f32_16x16x32_bf16(kf1, qf, z, 0, 0, 0);
        // lane holds S[q=q0+l15][keys kbase+4hi+r (s0), kbase+16+4hi+r (s1)]

        float mx = fmaxf(fmaxf(fmaxf(s0[0], s0[1]), fmaxf(s0[2], s0[3])),
                         fmaxf(fmaxf(s1[0], s1[1]), fmaxf(s1[2], s1[3])));
        mx = fmaxf(mx, __shfl_xor(mx, 16, 64));
        mx = fmaxf(mx, __shfl_xor(mx, 32, 64));

        if (__any(mx > mrun)) {
            float mnew = fmaxf(mrun, mx);
            float corr = EXP2F(mrun - mnew);
            mrun = mnew;
            lsum *= corr;
            cv0 *= corr; cv1 *= corr;
        }

        float p0[4], p1[4];
        #pragma unroll
        for (int r = 0; r < 4; r++) {
            p0[r] = EXP2F(s0[r] - mrun);
            p1[r] = EXP2F(s1[r] - mrun);
            lsum += p0[r] + p1[r];
        }

        // pack P into the PV A-fragment (virtual k = {4hi+r, 16+4hi+r})
        union { unsigned int u[4]; bf16x8 v; } pk_;
        asm("v_cvt_pk_bf16_f32 %0, %1, %2" : "=v"(pk_.u[0]) : "v"(p0[0]), "v"(p0[1]));
        asm("v_cvt_pk_bf16_f32 %0, %1, %2" : "=v"(pk_.u[1]) : "v"(p0[2]), "v"(p0[3]));
        asm("v_cvt_pk_bf16_f32 %0, %1, %2" : "=v"(pk_.u[2]) : "v"(p1[0]), "v"(p1[1]));
        asm("v_cvt_pk_bf16_f32 %0, %1, %2" : "=v"(pk_.u[3]) : "v"(p1[2]), "v"(p1[3]));

        // V B-fragments at the same permuted key offsets
        union { unsigned int u[4]; bf16x8 v; } vb0_, vb1_;
        uint2 a00 = *(const uint2*)(vrow0 + kbase + 4 * hi);
        uint2 a01 = *(const uint2*)(vrow0 + kbase + 16 + 4 * hi);
        uint2 a10 = *(const uint2*)(vrow1 + kbase + 4 * hi);
        uint2 a11 = *(const uint2*)(vrow1 + kbase + 16 + 4 * hi);
        vb0_.u[0] = a00.x; vb0_.u[1] = a00.y; vb0_.u[2] = a01.x; vb0_.u[3] = a01.y;
        vb1_.u[0] = a10.x; vb1_.u[1] = a10.y; vb1_.u[2] = a11.x; vb1_.u[3] = a11.y;

        cv0 = __builtin_amdgcn_mfma_f32_16x16x32_bf16(pk_.v, vb0_.v, cv0, 0, 0, 0);
        cv1 = __builtin_amdgcn_mfma_f32_16x16x32_bf16(pk_.v, vb1_.v, cv1, 0, 0, 0);
    }

    // total l for q=l15 over this wave's keys
    lsum += __shfl_xor(lsum, 16, 64);
    lsum += __shfl_xor(lsum, 32, 64);

    // merge the 4 key-split partials via LDS
    __shared__ float lm[4][16], ll[4][16];
    __shared__ float lo[4][16][34];
    if (hi == 0) { lm[w][l15] = mrun; ll[w][l15] = lsum; }
    #pragma unroll
    for (int r = 0; r < 4; r++) {
        lo[w][hi * 4 + r][l15]      = cv0[r];
        lo[w][hi * 4 + r][16 + l15] = cv1[r];
    }
    __syncthreads();

    int q = tid >> 4;
    int d0 = (tid & 15) * 2;
    float M = fmaxf(fmaxf(lm[0][q], lm[1][q]), fmaxf(lm[2][q], lm[3][q]));
    float wgt[4]; float L = 0.f;
    #pragma unroll
    for (int s = 0; s < 4; s++) { wgt[s] = EXP2F(lm[s][q] - M); L += ll[s][q] * wgt[s]; }
    float invL = 1.f / L;
    float2 o2;
    o2.x = (lo[0][q][d0]     * wgt[0] + lo[1][q][d0]     * wgt[1]
          + lo[2][q][d0]     * wgt[2] + lo[3][q][d0]     * wgt[3]) * invL;
    o2.y = (lo[0][q][d0 + 1] * wgt[0] + lo[1][q][d0 + 1] * wgt[1]
          + lo[2][q][d0 + 1] * wgt[2] + lo[3][q][d0 + 1] * wgt[3]) * invL;
    *(float2*)&O[((size_t)(b * NTOK + q0 + q)) * 256 + h * 32 + d0] = o2;
}

// ---------------- GAT pieces ----------------

__global__ __launch_bounds__(256) void k_attvec(const float* __restrict__ h,
    const float* __restrict__ wsrc, const float* __restrict__ wdst,
    float* __restrict__ a_src, float* __restrict__ a_dst)
{
    int node = blockIdx.x;
    int c = threadIdx.x;
    float hv = h[(size_t)node * CH + c];
    __shared__ float s1[4], s2[4];
    float a = hv * wsrc[c], q = hv * wdst[c];
    red2(a, q, s1, s2);
    if (c == 0) { a_src[node] = a; a_dst[node] = q; }
}

__global__ void k_fill_edges(const int* __restrict__ ei, int Eed,
    int* __restrict__ deg, int* __restrict__ csr)
{
    int e = blockIdx.x * 256 + threadIdx.x;
    if (e >= Eed) return;
    int src = ei[e];
    int dst = ei[Eed + e];
    int pos = atomicAdd(&deg[dst], 1);
    if (pos < 16) csr[dst * 16 + pos] = src;
}

__global__ __launch_bounds__(256) void k_gat_agg(const int* __restrict__ deg,
    const int* __restrict__ csr, const float* __restrict__ a_src,
    const float* __restrict__ a_dst, const float* __restrict__ h,
    const float* __restrict__ gbias, float* __restrict__ nf)
{
    int dst = blockIdx.x;
    int t = threadIdx.x;
    __shared__ float logit[16];
    __shared__ float alpha[16];
    __shared__ int srcs[16];
    int cnt = deg[dst]; if (cnt > 16) cnt = 16;
    if (t < cnt) {
        int s = csr[dst * 16 + t];
        srcs[t] = s;
        float lg = a_src[s] + a_dst[dst];
        logit[t] = lg > 0.f ? lg : 0.2f * lg;
    }
    __syncthreads();
    if (t == 0) {
        float mx = -1e30f;
        for (int i = 0; i < cnt; i++) mx = fmaxf(mx, logit[i]);
        float dn = 0.f;
        for (int i = 0; i < cnt; i++) { float ex = __expf(logit[i] - mx); alpha[i] = ex; dn += ex; }
        float inv = 1.f / (dn + 1e-16f);
        for (int i = 0; i < cnt; i++) alpha[i] *= inv;
    }
    __syncthreads();
    float accv = 0.f;
    for (int i = 0; i < cnt; i++) accv += alpha[i] * h[(size_t)srcs[i] * CH + t];
    float val = accv + gbias[t];
    val = val > 0.f ? val : expm1f(val);
    nf[(size_t)dst * CH + t] += val;
}

// ---------------- orchestration ----------------
extern "C" void kernel_launch(void* const* d_in, const int* in_sizes, int n_in,
                              void* d_out, int out_size, void* d_ws, size_t ws_size,
                              hipStream_t stream)
{
    const float* x_cnn   = (const float*)d_in[0];
    const int*   edge    = (const int*)d_in[1];
    const float* norm1_g = (const float*)d_in[2];
    const float* norm1_b = (const float*)d_in[3];
    const float* proj_w  = (const float*)d_in[4];
    const float* proj_b  = (const float*)d_in[5];
    const float* wq      = (const float*)d_in[6];
    const float* bq      = (const float*)d_in[7];
    const float* wk      = (const float*)d_in[8];
    const float* bk      = (const float*)d_in[9];
    const float* wv      = (const float*)d_in[10];
    const float* bv      = (const float*)d_in[11];
    const float* wo      = (const float*)d_in[12];
    const float* bo      = (const float*)d_in[13];
    const float* norm2_g = (const float*)d_in[14];
    const float* norm2_b = (const float*)d_in[15];
    const float* gpl_w   = (const float*)d_in[16];
    const float* gpl_b   = (const float*)d_in[17];
    const float* gat_w   = (const float*)d_in[18];
    const float* att_src = (const float*)d_in[19];
    const float* att_dst = (const float*)d_in[20];
    const float* gat_bias= (const float*)d_in[21];
    const float* norm3_g = (const float*)d_in[22];
    const float* norm3_b = (const float*)d_in[23];
    const float* mlp_w1  = (const float*)d_in[24];
    const float* mlp_b1  = (const float*)d_in[25];
    const float* mlp_w2  = (const float*)d_in[26];
    const float* mlp_b2  = (const float*)d_in[27];
    const float* fn_g    = (const float*)d_in[28];
    const float* fn_b    = (const float*)d_in[29];

    int Eed = in_sizes[1] / 2;
    float* out = (float*)d_out;

    const size_t NB = (size_t)NS * CH;   // 1,179,648
    float* ws   = (float*)d_ws;
    float* bufA = ws + 0 * NB;
    float* bufB = ws + 1 * NB;
    float* bufC = ws + 2 * NB;
    float* bufD = ws + 3 * NB;
    float* bufE = ws + 4 * NB;
    float* a_src = ws + 5 * NB;
    float* a_dst = a_src + NS;
    int*   deg   = (int*)(a_dst + NS);
    int*   csr   = deg + NS;             // NS*16 ints
    unsigned short* qb = (unsigned short*)(csr + (size_t)NS * 16);
    unsigned short* kb = qb + NB;
    unsigned short* vt = kb + NB;
    unsigned short* wt = vt + NB;        // 9 * 65536 bf16 transposed weights
    // total ws ≈ 33 MB

    // fold 1/sqrt(dh) AND log2(e) into q so softmax runs in exp2 domain
    const float qscale = 0.17677669529663687f * 1.4426950408889634f;
    dim3 gg(72, 8);       // 64x32 tiles over 4608x256
    dim3 gw(8, 8, 9);

    // 0. transpose+convert all weights to bf16 [n][k]
    k_wprep<<<gw, 256, 0, stream>>>(proj_w, wq, wk, wv, wo, gpl_w, gat_w,
                                    mlp_w1, mlp_w2, wt);
    // 1. tokenize + LN1 -> bufA
    k_ln_tok<<<NS, 256, 0, stream>>>(x_cnn, norm1_g, norm1_b, bufA);
    // 2. xv = bufA @ proj + proj_b -> bufB (fp32)
    k_gemm_mfma<0><<<gg, 256, 0, stream>>>(bufA, wt + 0 * 65536, proj_b, nullptr, bufB);
    // 3. fused q,k,v -> qb (scaled), kb, vt
    k_gemm_qkv<<<dim3(72, 8, 3), 256, 0, stream>>>(bufB, wt + 1 * 65536,
                                                   bq, bk, bv, qb, kb, vt, qscale);
    // 4. MFMA flash attention -> bufA
    k_attn_mfma<<<dim3(144, 16), 256, 0, stream>>>(qb, kb, vt, bufA);
    // 5. nf = bufB + bufA @ wo + bo  (in-place into bufB)
    k_gemm_mfma<0><<<gg, 256, 0, stream>>>(bufA, wt + 4 * 65536, bo, bufB, bufB);
    // 6. ln2 -> bufC
    k_ln<<<NS, 256, 0, stream>>>(bufB, norm2_g, norm2_b, bufC);
    // 7. xg = bufC @ gpl_w + gpl_b -> bufD
    k_gemm_mfma<0><<<gg, 256, 0, stream>>>(bufC, wt + 5 * 65536, gpl_b, nullptr, bufD);
    // 8. h = bufD @ gat_w -> bufE
    k_gemm_mfma<0><<<gg, 256, 0, stream>>>(bufD, wt + 6 * 65536, nullptr, nullptr, bufE);
    // 9. a_src/a_dst
    k_attvec<<<NS, 256, 0, stream>>>(bufE, att_src, att_dst, a_src, a_dst);
    // 10. CSR build
    (void)hipMemsetAsync(deg, 0, NS * sizeof(int), stream);
    k_fill_edges<<<(Eed + 255) / 256, 256, 0, stream>>>(edge, Eed, deg, csr);
    // 11. GAT aggregate + elu + residual (bufB updated in place)
    k_gat_agg<<<NS, 256, 0, stream>>>(deg, csr, a_src, a_dst, bufE, gat_bias, bufB);
    // 12. ln3 -> bufC
    k_ln<<<NS, 256, 0, stream>>>(bufB, norm3_g, norm3_b, bufC);
    // 13. mlp1 = gelu(bufC @ mlp_w1 + b1) -> bufD
    k_gemm_mfma<1><<<gg, 256, 0, stream>>>(bufC, wt + 7 * 65536, mlp_b1, nullptr, bufD);
    // 14. y_pre = bufC + bufD @ mlp_w2 + b2 -> bufA
    k_gemm_mfma<0><<<gg, 256, 0, stream>>>(bufD, wt + 8 * 65536, mlp_b2, bufC, bufA);
    // 15. final LN + transpose -> out
    k_ln_out<<<NS, 256, 0, stream>>>(bufA, fn_g, fn_b, out);
}

// Round 8
// 207.904 us; speedup vs baseline: 1.2020x; 1.2020x over previous
//
#include <hip/hip_runtime.h>
#include <math.h>

// Problem constants (B=2, H=W=48, C=E=256, NH=8, GH=1)
#define NTOK 2304              // H*W
#define NS   4608              // B*NTOK
#define CH   256               // C == E == E*GH

using bf16x8 = __attribute__((ext_vector_type(8))) short;
using f32x4  = __attribute__((ext_vector_type(4))) float;

#define EXP2F(x) __builtin_amdgcn_exp2f(x)

__device__ __forceinline__ unsigned short f2bf(float x) {
    unsigned int u = __float_as_uint(x);
    u = (u + 0x7fffu + ((u >> 16) & 1u)) >> 16;   // RNE
    return (unsigned short)u;
}

// ---------------- block LN reduce: wave shfl + 1 barrier ----------------
__device__ __forceinline__ void red2(float& a, float& b, float* s1, float* s2) {
    #pragma unroll
    for (int off = 32; off; off >>= 1) {
        a += __shfl_xor(a, off, 64);
        b += __shfl_xor(b, off, 64);
    }
    int t = threadIdx.x;
    if ((t & 63) == 0) { s1[t >> 6] = a; s2[t >> 6] = b; }
    __syncthreads();
    a = s1[0] + s1[1] + s1[2] + s1[3];
    b = s2[0] + s2[1] + s2[2] + s2[3];
}

// LN over channel dim while transposing [B,C,N] -> [Ns, C]
__global__ __launch_bounds__(256) void k_ln_tok(const float* __restrict__ x,
    const float* __restrict__ g, const float* __restrict__ be, float* __restrict__ out)
{
    int row = blockIdx.x;              // b*NTOK + n
    int b = row / NTOK, n = row - b * NTOK;
    int c = threadIdx.x;
    float v = x[((size_t)b * CH + c) * NTOK + n];
    __shared__ float s1[4], s2[4];
    float a = v, q = v * v;
    red2(a, q, s1, s2);
    float mu = a * (1.f / CH);
    float var = q * (1.f / CH) - mu * mu;
    float r = rsqrtf(var + 1e-5f);
    out[(size_t)row * CH + c] = (v - mu) * r * g[c] + be[c];
}

__global__ __launch_bounds__(256) void k_ln(const float* __restrict__ in,
    const float* __restrict__ g, const float* __restrict__ be, float* __restrict__ out)
{
    int row = blockIdx.x;
    int c = threadIdx.x;
    float v = in[(size_t)row * CH + c];
    __shared__ float s1[4], s2[4];
    float a = v, q = v * v;
    red2(a, q, s1, s2);
    float mu = a * (1.f / CH);
    float var = q * (1.f / CH) - mu * mu;
    float r = rsqrtf(var + 1e-5f);
    out[(size_t)row * CH + c] = (v - mu) * r * g[c] + be[c];
}

// final LN + transpose to [B, E, H*W]
__global__ __launch_bounds__(256) void k_ln_out(const float* __restrict__ in,
    const float* __restrict__ g, const float* __restrict__ be, float* __restrict__ out)
{
    int row = blockIdx.x;
    int b = row / NTOK, n = row - b * NTOK;
    int c = threadIdx.x;
    float v = in[(size_t)row * CH + c];
    __shared__ float s1[4], s2[4];
    float a = v, q = v * v;
    red2(a, q, s1, s2);
    float mu = a * (1.f / CH);
    float var = q * (1.f / CH) - mu * mu;
    float r = rsqrtf(var + 1e-5f);
    float val = (v - mu) * r * g[c] + be[c];
    out[((size_t)b * CH + c) * NTOK + n] = val;
}

// ---------------- weight prep: fp32 W[k][n] -> bf16 Wt[n][k], 9 matrices ----------------
__global__ __launch_bounds__(256) void k_wprep(
    const float* __restrict__ w0, const float* __restrict__ w1,
    const float* __restrict__ w2, const float* __restrict__ w3,
    const float* __restrict__ w4, const float* __restrict__ w5,
    const float* __restrict__ w6, const float* __restrict__ w7,
    const float* __restrict__ w8, unsigned short* __restrict__ wt)
{
    const float* W;
    switch (blockIdx.z) {
        case 0: W = w0; break; case 1: W = w1; break; case 2: W = w2; break;
        case 3: W = w3; break; case 4: W = w4; break; case 5: W = w5; break;
        case 6: W = w6; break; case 7: W = w7; break; default: W = w8; break;
    }
    unsigned short* out = wt + (size_t)blockIdx.z * 65536;
    __shared__ float fs[32][33];
    int tid = threadIdx.x;
    int bk = blockIdx.x * 32, bn = blockIdx.y * 32;
    int k = tid >> 3, n4 = (tid & 7) * 4;
    float4 v = *(const float4*)&W[(size_t)(bk + k) * 256 + bn + n4];
    fs[k][n4] = v.x; fs[k][n4 + 1] = v.y; fs[k][n4 + 2] = v.z; fs[k][n4 + 3] = v.w;
    __syncthreads();
    int n = tid >> 3, k4 = (tid & 7) * 4;
    ushort4 o;
    o.x = f2bf(fs[k4 + 0][n]); o.y = f2bf(fs[k4 + 1][n]);
    o.z = f2bf(fs[k4 + 2][n]); o.w = f2bf(fs[k4 + 3][n]);
    *(ushort4*)&out[(size_t)(bn + n) * 256 + bk + k4] = o;
}

// ======== single-barrier full-panel GEMM ========
// Stage the whole 64x256 A-panel as bf16 in LDS (XOR-swizzled 8-elem subtiles),
// ONE __syncthreads, then 8 unrolled k-steps of ds_read + global-B + MFMA.
// LN=1: fuse row LayerNorm into the prologue (quad shfl stats).
// Staging map: thread t -> row sr=t>>2, cols csel*4 + i*16 (i=0..15).
#define PANEL_STAGE(LNFLAG)                                                          \
    int sr = tid >> 2;                                                               \
    int csel = tid & 3;                                                              \
    const float* arow = A + (size_t)(bm + sr) * 256 + csel * 4;                      \
    float vals[64];                                                                  \
    float sum = 0.f, sq = 0.f;                                                       \
    _Pragma("unroll")                                                                \
    for (int i = 0; i < 16; i++) {                                                   \
        float4 v4 = *(const float4*)(arow + i * 16);                                 \
        vals[i*4+0] = v4.x; vals[i*4+1] = v4.y;                                      \
        vals[i*4+2] = v4.z; vals[i*4+3] = v4.w;                                      \
        if (LNFLAG) { sum += v4.x + v4.y + v4.z + v4.w;                              \
                      sq  += v4.x*v4.x + v4.y*v4.y + v4.z*v4.z + v4.w*v4.w; }        \
    }                                                                                \
    if (LNFLAG) {                                                                    \
        sum += __shfl_xor(sum, 1, 64); sum += __shfl_xor(sum, 2, 64);                \
        sq  += __shfl_xor(sq,  1, 64); sq  += __shfl_xor(sq,  2, 64);                \
        float mu = sum * (1.f/256.f);                                                \
        float rstd = rsqrtf(sq * (1.f/256.f) - mu*mu + 1e-5f);                       \
        _Pragma("unroll")                                                            \
        for (int i = 0; i < 16; i++) {                                               \
            float4 g4 = *(const float4*)&g[csel*4 + i*16];                           \
            float4 b4 = *(const float4*)&be[csel*4 + i*16];                          \
            vals[i*4+0] = (vals[i*4+0]-mu)*rstd*g4.x + b4.x;                         \
            vals[i*4+1] = (vals[i*4+1]-mu)*rstd*g4.y + b4.y;                         \
            vals[i*4+2] = (vals[i*4+2]-mu)*rstd*g4.z + b4.z;                         \
            vals[i*4+3] = (vals[i*4+3]-mu)*rstd*g4.w + b4.w;                         \
        }                                                                            \
    }                                                                                \
    int rx = sr & 7;                                                                 \
    _Pragma("unroll")                                                                \
    for (int i = 0; i < 16; i++) {                                                   \
        ushort4 u;                                                                   \
        u.x = f2bf(vals[i*4+0]); u.y = f2bf(vals[i*4+1]);                            \
        u.z = f2bf(vals[i*4+2]); u.w = f2bf(vals[i*4+3]);                            \
        int sub = 2*i + (csel >> 1);                                                 \
        *(ushort4*)&As[sr*256 + ((sub ^ rx) * 8) + (csel & 1) * 4] = u;              \
    }                                                                                \
    __syncthreads();

#define PANEL_MAINLOOP                                                               \
    int w = tid >> 6, l = tid & 63;                                                  \
    int l15 = l & 15, hi = l >> 4;                                                   \
    f32x4 acc0 = {0.f,0.f,0.f,0.f};                                                  \
    f32x4 acc1 = {0.f,0.f,0.f,0.f};                                                  \
    int ar2 = w*16 + l15, arx = ar2 & 7;                                             \
    _Pragma("unroll")                                                                \
    for (int kk = 0; kk < 256; kk += 32) {                                           \
        bf16x8 af = *(const bf16x8*)&As[ar2*256 + ((((kk>>3)+hi) ^ arx) * 8)];       \
        bf16x8 b0 = *(const bf16x8*)&Wt[(size_t)(bn + l15) * 256 + kk + hi * 8];     \
        bf16x8 b1 = *(const bf16x8*)&Wt[(size_t)(bn + 16 + l15) * 256 + kk + hi * 8];\
        acc0 = __builtin_amdgcn_mfma_f32_16x16x32_bf16(af, b0, acc0, 0, 0, 0);       \
        acc1 = __builtin_amdgcn_mfma_f32_16x16x32_bf16(af, b1, acc1, 0, 0, 0);       \
    }

template<int LN, int ACT>
__global__ __launch_bounds__(256) void k_gemm2(const float* __restrict__ A,
    const unsigned short* __restrict__ Wt,
    const float* __restrict__ g, const float* __restrict__ be,
    const float* __restrict__ bias, const float* __restrict__ resid,
    float* __restrict__ outf)
{
    __shared__ unsigned short As[64 * 256];
    int tid = threadIdx.x;
    int bm = blockIdx.x * 64, bn = blockIdx.y * 32;

    PANEL_STAGE(LN)
    PANEL_MAINLOOP

    #pragma unroll
    for (int j = 0; j < 2; j++) {
        #pragma unroll
        for (int r = 0; r < 4; r++) {
            float vv = (j == 0) ? acc0[r] : acc1[r];
            int gcol = bn + j * 16 + l15;
            int grow = bm + w * 16 + hi * 4 + r;   // C: col=lane&15, row=4*(l>>4)+reg
            if (bias) vv += bias[gcol];
            if (resid) vv += resid[(size_t)grow * 256 + gcol];
            if (ACT == 1) vv = 0.5f * vv * (1.f + erff(vv * 0.70710678118654752f));
            outf[(size_t)grow * 256 + gcol] = vv;
        }
    }
}

// fused QKV GEMM (panel version): z=0 -> qb (scaled), z=1 -> kb, z=2 -> vt
__global__ __launch_bounds__(256) void k_gemm_qkv(const float* __restrict__ A,
    const unsigned short* __restrict__ Wt3,
    const float* __restrict__ bq, const float* __restrict__ bk2, const float* __restrict__ bv,
    unsigned short* __restrict__ qb, unsigned short* __restrict__ kb,
    unsigned short* __restrict__ vt, float qscale)
{
    int z = blockIdx.z;
    const unsigned short* Wt = Wt3 + (size_t)z * 65536;
    const float* bias = (z == 0) ? bq : (z == 1) ? bk2 : bv;
    const float* g = nullptr; const float* be = nullptr; (void)g; (void)be;

    __shared__ unsigned short As[64 * 256];
    int tid = threadIdx.x;
    int bm = blockIdx.x * 64, bn = blockIdx.y * 32;

    PANEL_STAGE(0)
    PANEL_MAINLOOP

    float scale = (z == 0) ? qscale : 1.f;
    unsigned short* outqk = (z == 0) ? qb : kb;
    #pragma unroll
    for (int j = 0; j < 2; j++) {
        #pragma unroll
        for (int r = 0; r < 4; r++) {
            float vv = (j == 0) ? acc0[r] : acc1[r];
            int gcol = bn + j * 16 + l15;
            int grow = bm + w * 16 + hi * 4 + r;
            vv += bias[gcol];
            int b = grow >= NTOK;
            int tok = grow - b * NTOK;
            int h = gcol >> 5, d = gcol & 31;
            if (z < 2)
                outqk[(((size_t)(b * 8 + h)) * NTOK + tok) * 32 + d] = f2bf(vv * scale);
            else
                vt[((size_t)(b * 8 + h) * 32 + d) * NTOK + tok] = f2bf(vv);
        }
    }
}

// ---------------- MFMA flash attention (round-6 structure) ----------------
// block: 16 queries, 4 waves split the 2304 keys (576 each).
// q pre-scaled by (1/sqrt(dh))*log2(e) -> exp2 domain.
// Per 32-key step: S^T = mfma(K,Qt) x2; online softmax (defer-rescale);
// P packed via v_cvt_pk_bf16_f32, transposed through per-wave LDS
// (2x ds_write_b64 + 1x ds_read_b128); O^T += mfma(V^T, P) x2.
__global__ __launch_bounds__(256) void k_attn_mfma(
    const unsigned short* __restrict__ qb, const unsigned short* __restrict__ kb,
    const unsigned short* __restrict__ vt, float* __restrict__ O)
{
    int bh = blockIdx.y; int b = bh >> 3, h = bh & 7;
    int tid = threadIdx.x;
    int w = tid >> 6, l = tid & 63;
    int q15 = l & 15, hi = l >> 4;
    int q0 = blockIdx.x * 16;

    bf16x8 qf = *(const bf16x8*)(qb + ((size_t)bh * NTOK + q0 + q15) * 32 + hi * 8);

    f32x4 cv0 = {0.f, 0.f, 0.f, 0.f};
    f32x4 cv1 = {0.f, 0.f, 0.f, 0.f};
    float mrun = -1e30f, lsum = 0.f;

    const unsigned short* kbh = kb + (size_t)bh * NTOK * 32;
    const unsigned short* vbh = vt + (size_t)bh * 32 * NTOK;
    int kstart = w * (NTOK / 4);

    // per-wave P transpose buffer: [16 q][40 k] bf16
    __shared__ __align__(16) unsigned short plds[4][16 * 40];
    unsigned short* pl = plds[w];

    for (int kt = 0; kt < NTOK / 4; kt += 32) {
        int kbase = kstart + kt;
        bf16x8 kf0 = *(const bf16x8*)(kbh + (size_t)(kbase + q15) * 32 + hi * 8);
        bf16x8 kf1 = *(const bf16x8*)(kbh + (size_t)(kbase + 16 + q15) * 32 + hi * 8);
        f32x4 z = {0.f, 0.f, 0.f, 0.f};
        f32x4 s0 = __builtin_amdgcn_mfma_f32_16x16x32_bf16(kf0, qf, z, 0, 0, 0);
        f32x4 s1 = __builtin_amdgcn_mfma_f32_16x16x32_bf16(kf1, qf, z, 0, 0, 0);

        float mx = fmaxf(fmaxf(fmaxf(s0[0], s0[1]), fmaxf(s0[2], s0[3])),
                         fmaxf(fmaxf(s1[0], s1[1]), fmaxf(s1[2], s1[3])));
        mx = fmaxf(mx, __shfl_xor(mx, 16, 64));
        mx = fmaxf(mx, __shfl_xor(mx, 32, 64));

        if (__any(mx > mrun)) {
            float mnew = fmaxf(mrun, mx);
            float corr = EXP2F(mrun - mnew);
            mrun = mnew;
            lsum *= corr;
            cv0 *= corr; cv1 *= corr;
        }

        float p0[4], p1[4];
        #pragma unroll
        for (int r = 0; r < 4; r++) {
            p0[r] = EXP2F(s0[r] - mrun);
            p1[r] = EXP2F(s1[r] - mrun);
            lsum += p0[r] + p1[r];
        }

        unsigned int P0, P1, Q0, Q1;
        asm("v_cvt_pk_bf16_f32 %0, %1, %2" : "=v"(P0) : "v"(p0[0]), "v"(p0[1]));
        asm("v_cvt_pk_bf16_f32 %0, %1, %2" : "=v"(P1) : "v"(p0[2]), "v"(p0[3]));
        asm("v_cvt_pk_bf16_f32 %0, %1, %2" : "=v"(Q0) : "v"(p1[0]), "v"(p1[1]));
        asm("v_cvt_pk_bf16_f32 %0, %1, %2" : "=v"(Q1) : "v"(p1[2]), "v"(p1[3]));
        uint2 w0; w0.x = P0; w0.y = P1;
        uint2 w1; w1.x = Q0; w1.y = Q1;
        *(uint2*)(pl + q15 * 40 + hi * 4)      = w0;
        *(uint2*)(pl + q15 * 40 + 16 + hi * 4) = w1;
        bf16x8 pf = *(const bf16x8*)(pl + q15 * 40 + hi * 8);

        bf16x8 v0 = *(const bf16x8*)(vbh + (size_t)q15 * NTOK + kbase + hi * 8);
        bf16x8 v1 = *(const bf16x8*)(vbh + (size_t)(q15 + 16) * NTOK + kbase + hi * 8);

        cv0 = __builtin_amdgcn_mfma_f32_16x16x32_bf16(v0, pf, cv0, 0, 0, 0);
        cv1 = __builtin_amdgcn_mfma_f32_16x16x32_bf16(v1, pf, cv1, 0, 0, 0);
    }

    lsum += __shfl_xor(lsum, 16, 64);
    lsum += __shfl_xor(lsum, 32, 64);

    __shared__ float lm[4][16], ll[4][16];
    __shared__ float lo[4][16][32];
    if (hi == 0) { lm[w][q15] = mrun; ll[w][q15] = lsum; }
    #pragma unroll
    for (int r = 0; r < 4; r++) {
        lo[w][q15][hi * 4 + r]      = cv0[r];
        lo[w][q15][16 + hi * 4 + r] = cv1[r];
    }
    __syncthreads();

    int q = tid >> 4;
    int d0 = (tid & 15) * 2;
    float M = fmaxf(fmaxf(lm[0][q], lm[1][q]), fmaxf(lm[2][q], lm[3][q]));
    float wgt[4]; float L = 0.f;
    #pragma unroll
    for (int s = 0; s < 4; s++) { wgt[s] = EXP2F(lm[s][q] - M); L += ll[s][q] * wgt[s]; }
    float invL = 1.f / L;
    float2 o2;
    o2.x = (lo[0][q][d0]     * wgt[0] + lo[1][q][d0]     * wgt[1]
          + lo[2][q][d0]     * wgt[2] + lo[3][q][d0]     * wgt[3]) * invL;
    o2.y = (lo[0][q][d0 + 1] * wgt[0] + lo[1][q][d0 + 1] * wgt[1]
          + lo[2][q][d0 + 1] * wgt[2] + lo[3][q][d0 + 1] * wgt[3]) * invL;
    *(float2*)&O[((size_t)(b * NTOK + q0 + q)) * 256 + h * 32 + d0] = o2;
}

// ---------------- GAT pieces ----------------

__global__ __launch_bounds__(256) void k_attvec(const float* __restrict__ h,
    const float* __restrict__ wsrc, const float* __restrict__ wdst,
    float* __restrict__ a_src, float* __restrict__ a_dst)
{
    int node = blockIdx.x;
    int c = threadIdx.x;
    float hv = h[(size_t)node * CH + c];
    __shared__ float s1[4], s2[4];
    float a = hv * wsrc[c], q = hv * wdst[c];
    red2(a, q, s1, s2);
    if (c == 0) { a_src[node] = a; a_dst[node] = q; }
}

__global__ void k_fill_edges(const int* __restrict__ ei, int Eed,
    int* __restrict__ deg, int* __restrict__ csr)
{
    int e = blockIdx.x * 256 + threadIdx.x;
    if (e >= Eed) return;
    int src = ei[e];
    int dst = ei[Eed + e];
    int pos = atomicAdd(&deg[dst], 1);
    if (pos < 16) csr[dst * 16 + pos] = src;
}

__global__ __launch_bounds__(256) void k_gat_agg(const int* __restrict__ deg,
    const int* __restrict__ csr, const float* __restrict__ a_src,
    const float* __restrict__ a_dst, const float* __restrict__ h,
    const float* __restrict__ gbias, float* __restrict__ nf)
{
    int dst = blockIdx.x;
    int t = threadIdx.x;
    __shared__ float logit[16];
    __shared__ float alpha[16];
    __shared__ int srcs[16];
    int cnt = deg[dst]; if (cnt > 16) cnt = 16;
    if (t < cnt) {
        int s = csr[dst * 16 + t];
        srcs[t] = s;
        float lg = a_src[s] + a_dst[dst];
        logit[t] = lg > 0.f ? lg : 0.2f * lg;
    }
    __syncthreads();
    if (t == 0) {
        float mx = -1e30f;
        for (int i = 0; i < cnt; i++) mx = fmaxf(mx, logit[i]);
        float dn = 0.f;
        for (int i = 0; i < cnt; i++) { float ex = __expf(logit[i] - mx); alpha[i] = ex; dn += ex; }
        float inv = 1.f / (dn + 1e-16f);
        for (int i = 0; i < cnt; i++) alpha[i] *= inv;
    }
    __syncthreads();
    float accv = 0.f;
    for (int i = 0; i < cnt; i++) accv += alpha[i] * h[(size_t)srcs[i] * CH + t];
    float val = accv + gbias[t];
    val = val > 0.f ? val : expm1f(val);
    nf[(size_t)dst * CH + t] += val;
}

// ---------------- orchestration ----------------
extern "C" void kernel_launch(void* const* d_in, const int* in_sizes, int n_in,
                              void* d_out, int out_size, void* d_ws, size_t ws_size,
                              hipStream_t stream)
{
    const float* x_cnn   = (const float*)d_in[0];
    const int*   edge    = (const int*)d_in[1];
    const float* norm1_g = (const float*)d_in[2];
    const float* norm1_b = (const float*)d_in[3];
    const float* proj_w  = (const float*)d_in[4];
    const float* proj_b  = (const float*)d_in[5];
    const float* wq      = (const float*)d_in[6];
    const float* bq      = (const float*)d_in[7];
    const float* wk      = (const float*)d_in[8];
    const float* bk      = (const float*)d_in[9];
    const float* wv      = (const float*)d_in[10];
    const float* bv      = (const float*)d_in[11];
    const float* wo      = (const float*)d_in[12];
    const float* bo      = (const float*)d_in[13];
    const float* norm2_g = (const float*)d_in[14];
    const float* norm2_b = (const float*)d_in[15];
    const float* gpl_w   = (const float*)d_in[16];
    const float* gpl_b   = (const float*)d_in[17];
    const float* gat_w   = (const float*)d_in[18];
    const float* att_src = (const float*)d_in[19];
    const float* att_dst = (const float*)d_in[20];
    const float* gat_bias= (const float*)d_in[21];
    const float* norm3_g = (const float*)d_in[22];
    const float* norm3_b = (const float*)d_in[23];
    const float* mlp_w1  = (const float*)d_in[24];
    const float* mlp_b1  = (const float*)d_in[25];
    const float* mlp_w2  = (const float*)d_in[26];
    const float* mlp_b2  = (const float*)d_in[27];
    const float* fn_g    = (const float*)d_in[28];
    const float* fn_b    = (const float*)d_in[29];

    int Eed = in_sizes[1] / 2;
    float* out = (float*)d_out;

    const size_t NB = (size_t)NS * CH;   // 1,179,648
    float* ws   = (float*)d_ws;
    float* bufA = ws + 0 * NB;
    float* bufB = ws + 1 * NB;
    float* bufC = ws + 2 * NB;
    float* bufD = ws + 3 * NB;
    float* bufE = ws + 4 * NB;
    float* a_src = ws + 5 * NB;
    float* a_dst = a_src + NS;
    int*   deg   = (int*)(a_dst + NS);
    int*   csr   = deg + NS;             // NS*16 ints
    unsigned short* qb = (unsigned short*)(csr + (size_t)NS * 16);
    unsigned short* kb = qb + NB;
    unsigned short* vt = kb + NB;
    unsigned short* wt = vt + NB;        // 9 * 65536 bf16 transposed weights
    // total ws ≈ 33 MB

    // fold 1/sqrt(dh) AND log2(e) into q so softmax runs in exp2 domain
    const float qscale = 0.17677669529663687f * 1.4426950408889634f;
    dim3 gg(72, 8);       // 64x32 tiles over 4608x256
    dim3 gw(8, 8, 9);

    // 0. transpose+convert all weights to bf16 [n][k]
    k_wprep<<<gw, 256, 0, stream>>>(proj_w, wq, wk, wv, wo, gpl_w, gat_w,
                                    mlp_w1, mlp_w2, wt);
    // 1. tokenize + LN1 -> bufA
    k_ln_tok<<<NS, 256, 0, stream>>>(x_cnn, norm1_g, norm1_b, bufA);
    // 2. xv = bufA @ proj + proj_b -> bufB (fp32)
    k_gemm2<0,0><<<gg, 256, 0, stream>>>(bufA, wt + 0 * 65536, nullptr, nullptr,
                                         proj_b, nullptr, bufB);
    // 3. fused q,k,v -> qb (scaled), kb, vt
    k_gemm_qkv<<<dim3(72, 8, 3), 256, 0, stream>>>(bufB, wt + 1 * 65536,
                                                   bq, bk, bv, qb, kb, vt, qscale);
    // 4. MFMA flash attention -> bufA
    k_attn_mfma<<<dim3(144, 16), 256, 0, stream>>>(qb, kb, vt, bufA);
    // 5. nf = bufB + bufA @ wo + bo  (in-place into bufB)
    k_gemm2<0,0><<<gg, 256, 0, stream>>>(bufA, wt + 4 * 65536, nullptr, nullptr,
                                         bo, bufB, bufB);
    // 6+7. xg = LN2(bufB) @ gpl_w + gpl_b -> bufD   (LN fused into GEMM prologue)
    k_gemm2<1,0><<<gg, 256, 0, stream>>>(bufB, wt + 5 * 65536, norm2_g, norm2_b,
                                         gpl_b, nullptr, bufD);
    // 8. h = bufD @ gat_w -> bufE
    k_gemm2<0,0><<<gg, 256, 0, stream>>>(bufD, wt + 6 * 65536, nullptr, nullptr,
                                         nullptr, nullptr, bufE);
    // 9. a_src/a_dst
    k_attvec<<<NS, 256, 0, stream>>>(bufE, att_src, att_dst, a_src, a_dst);
    // 10. CSR build
    (void)hipMemsetAsync(deg, 0, NS * sizeof(int), stream);
    k_fill_edges<<<(Eed + 255) / 256, 256, 0, stream>>>(edge, Eed, deg, csr);
    // 11. GAT aggregate + elu + residual (bufB updated in place)
    k_gat_agg<<<NS, 256, 0, stream>>>(deg, csr, a_src, a_dst, bufE, gat_bias, bufB);
    // 12. ln3 -> bufC (xn needed twice: mlp input and final residual)
    k_ln<<<NS, 256, 0, stream>>>(bufB, norm3_g, norm3_b, bufC);
    // 13. mlp1 = gelu(bufC @ mlp_w1 + b1) -> bufD
    k_gemm2<0,1><<<gg, 256, 0, stream>>>(bufC, wt + 7 * 65536, nullptr, nullptr,
                                         mlp_b1, nullptr, bufD);
    // 14. y_pre = bufC + bufD @ mlp_w2 + b2 -> bufA
    k_gemm2<0,0><<<gg, 256, 0, stream>>>(bufD, wt + 8 * 65536, nullptr, nullptr,
                                         mlp_b2, bufC, bufA);
    // 15. final LN + transpose -> out
    k_ln_out<<<NS, 256, 0, stream>>>(bufA, fn_g, fn_b, out);
}

// Round 9
// 181.284 us; speedup vs baseline: 1.3785x; 1.1468x over previous
//
#include <hip/hip_runtime.h>
#include <math.h>

// Problem constants (B=2, H=W=48, C=E=256, NH=8, GH=1)
#define NTOK 2304              // H*W
#define NS   4608              // B*NTOK
#define CH   256               // C == E == E*GH

using bf16x8 = __attribute__((ext_vector_type(8))) short;
using f32x4  = __attribute__((ext_vector_type(4))) float;

#define EXP2F(x) __builtin_amdgcn_exp2f(x)

__device__ __forceinline__ unsigned short f2bf(float x) {
    unsigned int u = __float_as_uint(x);
    u = (u + 0x7fffu + ((u >> 16) & 1u)) >> 16;   // RNE
    return (unsigned short)u;
}

// ---------------- block LN reduce: wave shfl + 1 barrier ----------------
__device__ __forceinline__ void red2(float& a, float& b, float* s1, float* s2) {
    #pragma unroll
    for (int off = 32; off; off >>= 1) {
        a += __shfl_xor(a, off, 64);
        b += __shfl_xor(b, off, 64);
    }
    int t = threadIdx.x;
    if ((t & 63) == 0) { s1[t >> 6] = a; s2[t >> 6] = b; }
    __syncthreads();
    a = s1[0] + s1[1] + s1[2] + s1[3];
    b = s2[0] + s2[1] + s2[2] + s2[3];
}

// LN over channel dim while transposing [B,C,N] -> [Ns, C]
__global__ __launch_bounds__(256) void k_ln_tok(const float* __restrict__ x,
    const float* __restrict__ g, const float* __restrict__ be, float* __restrict__ out)
{
    int row = blockIdx.x;              // b*NTOK + n
    int b = row / NTOK, n = row - b * NTOK;
    int c = threadIdx.x;
    float v = x[((size_t)b * CH + c) * NTOK + n];
    __shared__ float s1[4], s2[4];
    float a = v, q = v * v;
    red2(a, q, s1, s2);
    float mu = a * (1.f / CH);
    float var = q * (1.f / CH) - mu * mu;
    float r = rsqrtf(var + 1e-5f);
    out[(size_t)row * CH + c] = (v - mu) * r * g[c] + be[c];
}

// final LN + transpose to [B, E, H*W]
__global__ __launch_bounds__(256) void k_ln_out(const float* __restrict__ in,
    const float* __restrict__ g, const float* __restrict__ be, float* __restrict__ out)
{
    int row = blockIdx.x;
    int b = row / NTOK, n = row - b * NTOK;
    int c = threadIdx.x;
    float v = in[(size_t)row * CH + c];
    __shared__ float s1[4], s2[4];
    float a = v, q = v * v;
    red2(a, q, s1, s2);
    float mu = a * (1.f / CH);
    float var = q * (1.f / CH) - mu * mu;
    float r = rsqrtf(var + 1e-5f);
    float val = (v - mu) * r * g[c] + be[c];
    out[((size_t)b * CH + c) * NTOK + n] = val;
}

// ---------------- weight prep: fp32 W[k][n] -> bf16 Wt[n][k], 9 matrices ----------------
__global__ __launch_bounds__(256) void k_wprep(
    const float* __restrict__ w0, const float* __restrict__ w1,
    const float* __restrict__ w2, const float* __restrict__ w3,
    const float* __restrict__ w4, const float* __restrict__ w5,
    const float* __restrict__ w6, const float* __restrict__ w7,
    const float* __restrict__ w8, unsigned short* __restrict__ wt)
{
    const float* W;
    switch (blockIdx.z) {
        case 0: W = w0; break; case 1: W = w1; break; case 2: W = w2; break;
        case 3: W = w3; break; case 4: W = w4; break; case 5: W = w5; break;
        case 6: W = w6; break; case 7: W = w7; break; default: W = w8; break;
    }
    unsigned short* out = wt + (size_t)blockIdx.z * 65536;
    __shared__ float fs[32][33];
    int tid = threadIdx.x;
    int bk = blockIdx.x * 32, bn = blockIdx.y * 32;
    int k = tid >> 3, n4 = (tid & 7) * 4;
    float4 v = *(const float4*)&W[(size_t)(bk + k) * 256 + bn + n4];
    fs[k][n4] = v.x; fs[k][n4 + 1] = v.y; fs[k][n4 + 2] = v.z; fs[k][n4 + 3] = v.w;
    __syncthreads();
    int n = tid >> 3, k4 = (tid & 7) * 4;
    ushort4 o;
    o.x = f2bf(fs[k4 + 0][n]); o.y = f2bf(fs[k4 + 1][n]);
    o.z = f2bf(fs[k4 + 2][n]); o.w = f2bf(fs[k4 + 3][n]);
    *(ushort4*)&out[(size_t)(bn + n) * 256 + bk + k4] = o;
}

// ======== single-barrier full-panel GEMM ========
// Stage the whole 64x256 A-panel as bf16 in LDS (XOR-swizzled 8-elem subtiles),
// ONE __syncthreads, then 8 unrolled k-steps of ds_read + global-B + MFMA.
// LN=1: fuse row LayerNorm into the prologue (quad shfl stats).
// WX=1: blocks with blockIdx.y==0 also write the normalized rows (fp32) to xout.
#define PANEL_STAGE(LNFLAG)                                                          \
    int sr = tid >> 2;                                                               \
    int csel = tid & 3;                                                              \
    const float* arow = A + (size_t)(bm + sr) * 256 + csel * 4;                      \
    float vals[64];                                                                  \
    float sum = 0.f, sq = 0.f;                                                       \
    _Pragma("unroll")                                                                \
    for (int i = 0; i < 16; i++) {                                                   \
        float4 v4 = *(const float4*)(arow + i * 16);                                 \
        vals[i*4+0] = v4.x; vals[i*4+1] = v4.y;                                      \
        vals[i*4+2] = v4.z; vals[i*4+3] = v4.w;                                      \
        if (LNFLAG) { sum += v4.x + v4.y + v4.z + v4.w;                              \
                      sq  += v4.x*v4.x + v4.y*v4.y + v4.z*v4.z + v4.w*v4.w; }        \
    }                                                                                \
    if (LNFLAG) {                                                                    \
        sum += __shfl_xor(sum, 1, 64); sum += __shfl_xor(sum, 2, 64);                \
        sq  += __shfl_xor(sq,  1, 64); sq  += __shfl_xor(sq,  2, 64);                \
        float mu = sum * (1.f/256.f);                                                \
        float rstd = rsqrtf(sq * (1.f/256.f) - mu*mu + 1e-5f);                       \
        _Pragma("unroll")                                                            \
        for (int i = 0; i < 16; i++) {                                               \
            float4 g4 = *(const float4*)&g[csel*4 + i*16];                           \
            float4 b4 = *(const float4*)&be[csel*4 + i*16];                          \
            vals[i*4+0] = (vals[i*4+0]-mu)*rstd*g4.x + b4.x;                         \
            vals[i*4+1] = (vals[i*4+1]-mu)*rstd*g4.y + b4.y;                         \
            vals[i*4+2] = (vals[i*4+2]-mu)*rstd*g4.z + b4.z;                         \
            vals[i*4+3] = (vals[i*4+3]-mu)*rstd*g4.w + b4.w;                         \
        }                                                                            \
    }                                                                                \
    int rx = sr & 7;                                                                 \
    _Pragma("unroll")                                                                \
    for (int i = 0; i < 16; i++) {                                                   \
        ushort4 u;                                                                   \
        u.x = f2bf(vals[i*4+0]); u.y = f2bf(vals[i*4+1]);                            \
        u.z = f2bf(vals[i*4+2]); u.w = f2bf(vals[i*4+3]);                            \
        int sub = 2*i + (csel >> 1);                                                 \
        *(ushort4*)&As[sr*256 + ((sub ^ rx) * 8) + (csel & 1) * 4] = u;              \
    }

#define PANEL_MAINLOOP                                                               \
    int w = tid >> 6, l = tid & 63;                                                  \
    int l15 = l & 15, hi = l >> 4;                                                   \
    f32x4 acc0 = {0.f,0.f,0.f,0.f};                                                  \
    f32x4 acc1 = {0.f,0.f,0.f,0.f};                                                  \
    int ar2 = w*16 + l15, arx = ar2 & 7;                                             \
    _Pragma("unroll")                                                                \
    for (int kk = 0; kk < 256; kk += 32) {                                           \
        bf16x8 af = *(const bf16x8*)&As[ar2*256 + ((((kk>>3)+hi) ^ arx) * 8)];       \
        bf16x8 b0 = *(const bf16x8*)&Wt[(size_t)(bn + l15) * 256 + kk + hi * 8];     \
        bf16x8 b1 = *(const bf16x8*)&Wt[(size_t)(bn + 16 + l15) * 256 + kk + hi * 8];\
        acc0 = __builtin_amdgcn_mfma_f32_16x16x32_bf16(af, b0, acc0, 0, 0, 0);       \
        acc1 = __builtin_amdgcn_mfma_f32_16x16x32_bf16(af, b1, acc1, 0, 0, 0);       \
    }

template<int LN, int ACT, int WX>
__global__ __launch_bounds__(256) void k_gemm2(const float* __restrict__ A,
    const unsigned short* __restrict__ Wt,
    const float* __restrict__ g, const float* __restrict__ be,
    const float* __restrict__ bias, const float* __restrict__ resid,
    float* __restrict__ outf, float* __restrict__ xout)
{
    __shared__ unsigned short As[64 * 256];
    int tid = threadIdx.x;
    int bm = blockIdx.x * 64, bn = blockIdx.y * 32;

    PANEL_STAGE(LN)
    if (WX) {
        if (blockIdx.y == 0) {
            #pragma unroll
            for (int i = 0; i < 16; i++) {
                float4 x4;
                x4.x = vals[i*4+0]; x4.y = vals[i*4+1];
                x4.z = vals[i*4+2]; x4.w = vals[i*4+3];
                *(float4*)&xout[(size_t)(bm + sr) * 256 + csel * 4 + i * 16] = x4;
            }
        }
    }
    __syncthreads();
    PANEL_MAINLOOP

    #pragma unroll
    for (int j = 0; j < 2; j++) {
        #pragma unroll
        for (int r = 0; r < 4; r++) {
            float vv = (j == 0) ? acc0[r] : acc1[r];
            int gcol = bn + j * 16 + l15;
            int grow = bm + w * 16 + hi * 4 + r;   // C: col=lane&15, row=4*(l>>4)+reg
            if (bias) vv += bias[gcol];
            if (resid) vv += resid[(size_t)grow * 256 + gcol];
            if (ACT == 1) vv = 0.5f * vv * (1.f + erff(vv * 0.70710678118654752f));
            outf[(size_t)grow * 256 + gcol] = vv;
        }
    }
}

// fused QKV GEMM (panel version): z=0 -> qb (scaled), z=1 -> kb, z=2 -> vt
__global__ __launch_bounds__(256) void k_gemm_qkv(const float* __restrict__ A,
    const unsigned short* __restrict__ Wt3,
    const float* __restrict__ bq, const float* __restrict__ bk2, const float* __restrict__ bv,
    unsigned short* __restrict__ qb, unsigned short* __restrict__ kb,
    unsigned short* __restrict__ vt, float qscale)
{
    int z = blockIdx.z;
    const unsigned short* Wt = Wt3 + (size_t)z * 65536;
    const float* bias = (z == 0) ? bq : (z == 1) ? bk2 : bv;
    const float* g = nullptr; const float* be = nullptr; (void)g; (void)be;

    __shared__ unsigned short As[64 * 256];
    int tid = threadIdx.x;
    int bm = blockIdx.x * 64, bn = blockIdx.y * 32;

    PANEL_STAGE(0)
    __syncthreads();
    PANEL_MAINLOOP

    float scale = (z == 0) ? qscale : 1.f;
    unsigned short* outqk = (z == 0) ? qb : kb;
    #pragma unroll
    for (int j = 0; j < 2; j++) {
        #pragma unroll
        for (int r = 0; r < 4; r++) {
            float vv = (j == 0) ? acc0[r] : acc1[r];
            int gcol = bn + j * 16 + l15;
            int grow = bm + w * 16 + hi * 4 + r;
            vv += bias[gcol];
            int b = grow >= NTOK;
            int tok = grow - b * NTOK;
            int h = gcol >> 5, d = gcol & 31;
            if (z < 2)
                outqk[(((size_t)(b * 8 + h)) * NTOK + tok) * 32 + d] = f2bf(vv * scale);
            else
                vt[((size_t)(b * 8 + h) * 32 + d) * NTOK + tok] = f2bf(vv);
        }
    }
}

// ---------------- MFMA flash attention: 32 queries/block, 2 q-tiles/wave ----------------
// 4 waves split the 2304 keys (576 each). Two 16-q tiles (A,B) share the K/V
// fragment loads; independent softmax chains give 2x ILP for latency hiding.
// q pre-scaled by (1/sqrt(dh))*log2(e) -> exp2 domain. Defer-rescale per tile.
__global__ __launch_bounds__(256) void k_attn_mfma(
    const unsigned short* __restrict__ qb, const unsigned short* __restrict__ kb,
    const unsigned short* __restrict__ vt, float* __restrict__ O)
{
    int bh = blockIdx.y; int b = bh >> 3, h = bh & 7;
    int tid = threadIdx.x;
    int w = tid >> 6, l = tid & 63;
    int q15 = l & 15, hi = l >> 4;
    int q0 = blockIdx.x * 32;

    const unsigned short* qbh = qb + (size_t)bh * NTOK * 32;
    bf16x8 qfA = *(const bf16x8*)(qbh + (size_t)(q0 + q15) * 32 + hi * 8);
    bf16x8 qfB = *(const bf16x8*)(qbh + (size_t)(q0 + 16 + q15) * 32 + hi * 8);

    f32x4 cvA0 = {0.f,0.f,0.f,0.f}, cvA1 = {0.f,0.f,0.f,0.f};
    f32x4 cvB0 = {0.f,0.f,0.f,0.f}, cvB1 = {0.f,0.f,0.f,0.f};
    float mA = -1e30f, lAs = 0.f, mB = -1e30f, lBs = 0.f;

    const unsigned short* kbh = kb + (size_t)bh * NTOK * 32;
    const unsigned short* vbh = vt + (size_t)bh * 32 * NTOK;
    int kstart = w * (NTOK / 4);

    // per-wave P transpose buffers: two [16 q][40 k] bf16 tiles
    __shared__ __align__(16) unsigned short plds[4][2 * 16 * 40];
    unsigned short* plA = plds[w];
    unsigned short* plB = plds[w] + 640;

    for (int kt = 0; kt < NTOK / 4; kt += 32) {
        int kbase = kstart + kt;
        bf16x8 kf0 = *(const bf16x8*)(kbh + (size_t)(kbase + q15) * 32 + hi * 8);
        bf16x8 kf1 = *(const bf16x8*)(kbh + (size_t)(kbase + 16 + q15) * 32 + hi * 8);
        f32x4 z = {0.f, 0.f, 0.f, 0.f};
        f32x4 sA0 = __builtin_amdgcn_mfma_f32_16x16x32_bf16(kf0, qfA, z, 0, 0, 0);
        f32x4 sA1 = __builtin_amdgcn_mfma_f32_16x16x32_bf16(kf1, qfA, z, 0, 0, 0);
        f32x4 sB0 = __builtin_amdgcn_mfma_f32_16x16x32_bf16(kf0, qfB, z, 0, 0, 0);
        f32x4 sB1 = __builtin_amdgcn_mfma_f32_16x16x32_bf16(kf1, qfB, z, 0, 0, 0);

        float mxA = fmaxf(fmaxf(fmaxf(sA0[0], sA0[1]), fmaxf(sA0[2], sA0[3])),
                          fmaxf(fmaxf(sA1[0], sA1[1]), fmaxf(sA1[2], sA1[3])));
        float mxB = fmaxf(fmaxf(fmaxf(sB0[0], sB0[1]), fmaxf(sB0[2], sB0[3])),
                          fmaxf(fmaxf(sB1[0], sB1[1]), fmaxf(sB1[2], sB1[3])));
        mxA = fmaxf(mxA, __shfl_xor(mxA, 16, 64));
        mxA = fmaxf(mxA, __shfl_xor(mxA, 32, 64));
        mxB = fmaxf(mxB, __shfl_xor(mxB, 16, 64));
        mxB = fmaxf(mxB, __shfl_xor(mxB, 32, 64));

        if (__any(mxA > mA)) {
            float mn = fmaxf(mA, mxA);
            float c = EXP2F(mA - mn);
            mA = mn; lAs *= c; cvA0 *= c; cvA1 *= c;
        }
        if (__any(mxB > mB)) {
            float mn = fmaxf(mB, mxB);
            float c = EXP2F(mB - mn);
            mB = mn; lBs *= c; cvB0 *= c; cvB1 *= c;
        }

        float pA0[4], pA1[4], pB0[4], pB1[4];
        #pragma unroll
        for (int r = 0; r < 4; r++) {
            pA0[r] = EXP2F(sA0[r] - mA);
            pA1[r] = EXP2F(sA1[r] - mA);
            pB0[r] = EXP2F(sB0[r] - mB);
            pB1[r] = EXP2F(sB1[r] - mB);
            lAs += pA0[r] + pA1[r];
            lBs += pB0[r] + pB1[r];
        }

        unsigned int A0, A1, A2, A3, B0, B1, B2, B3;
        asm("v_cvt_pk_bf16_f32 %0, %1, %2" : "=v"(A0) : "v"(pA0[0]), "v"(pA0[1]));
        asm("v_cvt_pk_bf16_f32 %0, %1, %2" : "=v"(A1) : "v"(pA0[2]), "v"(pA0[3]));
        asm("v_cvt_pk_bf16_f32 %0, %1, %2" : "=v"(A2) : "v"(pA1[0]), "v"(pA1[1]));
        asm("v_cvt_pk_bf16_f32 %0, %1, %2" : "=v"(A3) : "v"(pA1[2]), "v"(pA1[3]));
        asm("v_cvt_pk_bf16_f32 %0, %1, %2" : "=v"(B0) : "v"(pB0[0]), "v"(pB0[1]));
        asm("v_cvt_pk_bf16_f32 %0, %1, %2" : "=v"(B1) : "v"(pB0[2]), "v"(pB0[3]));
        asm("v_cvt_pk_bf16_f32 %0, %1, %2" : "=v"(B2) : "v"(pB1[0]), "v"(pB1[1]));
        asm("v_cvt_pk_bf16_f32 %0, %1, %2" : "=v"(B3) : "v"(pB1[2]), "v"(pB1[3]));
        uint2 wA0; wA0.x = A0; wA0.y = A1;
        uint2 wA1; wA1.x = A2; wA1.y = A3;
        uint2 wB0; wB0.x = B0; wB0.y = B1;
        uint2 wB1; wB1.x = B2; wB1.y = B3;
        *(uint2*)(plA + q15 * 40 + hi * 4)      = wA0;
        *(uint2*)(plA + q15 * 40 + 16 + hi * 4) = wA1;
        *(uint2*)(plB + q15 * 40 + hi * 4)      = wB0;
        *(uint2*)(plB + q15 * 40 + 16 + hi * 4) = wB1;
        bf16x8 pfA = *(const bf16x8*)(plA + q15 * 40 + hi * 8);
        bf16x8 pfB = *(const bf16x8*)(plB + q15 * 40 + hi * 8);

        bf16x8 v0 = *(const bf16x8*)(vbh + (size_t)q15 * NTOK + kbase + hi * 8);
        bf16x8 v1 = *(const bf16x8*)(vbh + (size_t)(q15 + 16) * NTOK + kbase + hi * 8);

        cvA0 = __builtin_amdgcn_mfma_f32_16x16x32_bf16(v0, pfA, cvA0, 0, 0, 0);
        cvA1 = __builtin_amdgcn_mfma_f32_16x16x32_bf16(v1, pfA, cvA1, 0, 0, 0);
        cvB0 = __builtin_amdgcn_mfma_f32_16x16x32_bf16(v0, pfB, cvB0, 0, 0, 0);
        cvB1 = __builtin_amdgcn_mfma_f32_16x16x32_bf16(v1, pfB, cvB1, 0, 0, 0);
    }

    lAs += __shfl_xor(lAs, 16, 64);
    lAs += __shfl_xor(lAs, 32, 64);
    lBs += __shfl_xor(lBs, 16, 64);
    lBs += __shfl_xor(lBs, 32, 64);

    // merge the 4 key-split partials via LDS
    __shared__ float lm[4][32], ll[4][32];
    __shared__ float lo[4][32][36];
    if (hi == 0) {
        lm[w][q15] = mA;      ll[w][q15] = lAs;
        lm[w][16 + q15] = mB; ll[w][16 + q15] = lBs;
    }
    #pragma unroll
    for (int r = 0; r < 4; r++) {
        lo[w][q15][hi * 4 + r]           = cvA0[r];
        lo[w][q15][16 + hi * 4 + r]      = cvA1[r];
        lo[w][16 + q15][hi * 4 + r]      = cvB0[r];
        lo[w][16 + q15][16 + hi * 4 + r] = cvB1[r];
    }
    __syncthreads();

    int q = tid >> 3;            // 0..31
    int d0 = (tid & 7) * 4;      // 0..28
    float M = fmaxf(fmaxf(lm[0][q], lm[1][q]), fmaxf(lm[2][q], lm[3][q]));
    float wgt[4]; float L = 0.f;
    #pragma unroll
    for (int s = 0; s < 4; s++) { wgt[s] = EXP2F(lm[s][q] - M); L += ll[s][q] * wgt[s]; }
    float invL = 1.f / L;
    float4 o4;
    float* po = (float*)&o4;
    #pragma unroll
    for (int dd = 0; dd < 4; dd++) {
        po[dd] = (lo[0][q][d0 + dd] * wgt[0] + lo[1][q][d0 + dd] * wgt[1]
                + lo[2][q][d0 + dd] * wgt[2] + lo[3][q][d0 + dd] * wgt[3]) * invL;
    }
    *(float4*)&O[((size_t)(b * NTOK + q0 + q)) * 256 + h * 32 + d0] = o4;
}

// ---------------- GAT pieces ----------------

__global__ __launch_bounds__(256) void k_attvec(const float* __restrict__ h,
    const float* __restrict__ wsrc, const float* __restrict__ wdst,
    float* __restrict__ a_src, float* __restrict__ a_dst)
{
    int node = blockIdx.x;
    int c = threadIdx.x;
    float hv = h[(size_t)node * CH + c];
    __shared__ float s1[4], s2[4];
    float a = hv * wsrc[c], q = hv * wdst[c];
    red2(a, q, s1, s2);
    if (c == 0) { a_src[node] = a; a_dst[node] = q; }
}

__global__ void k_fill_edges(const int* __restrict__ ei, int Eed,
    int* __restrict__ deg, int* __restrict__ csr)
{
    int e = blockIdx.x * 256 + threadIdx.x;
    if (e >= Eed) return;
    int src = ei[e];
    int dst = ei[Eed + e];
    int pos = atomicAdd(&deg[dst], 1);
    if (pos < 16) csr[dst * 16 + pos] = src;
}

__global__ __launch_bounds__(256) void k_gat_agg(const int* __restrict__ deg,
    const int* __restrict__ csr, const float* __restrict__ a_src,
    const float* __restrict__ a_dst, const float* __restrict__ h,
    const float* __restrict__ gbias, float* __restrict__ nf)
{
    int dst = blockIdx.x;
    int t = threadIdx.x;
    __shared__ float logit[16];
    __shared__ float alpha[16];
    __shared__ int srcs[16];
    int cnt = deg[dst]; if (cnt > 16) cnt = 16;
    if (t < cnt) {
        int s = csr[dst * 16 + t];
        srcs[t] = s;
        float lg = a_src[s] + a_dst[dst];
        logit[t] = lg > 0.f ? lg : 0.2f * lg;
    }
    __syncthreads();
    if (t == 0) {
        float mx = -1e30f;
        for (int i = 0; i < cnt; i++) mx = fmaxf(mx, logit[i]);
        float dn = 0.f;
        for (int i = 0; i < cnt; i++) { float ex = __expf(logit[i] - mx); alpha[i] = ex; dn += ex; }
        float inv = 1.f / (dn + 1e-16f);
        for (int i = 0; i < cnt; i++) alpha[i] *= inv;
    }
    __syncthreads();
    float accv = 0.f;
    for (int i = 0; i < cnt; i++) accv += alpha[i] * h[(size_t)srcs[i] * CH + t];
    float val = accv + gbias[t];
    val = val > 0.f ? val : expm1f(val);
    nf[(size_t)dst * CH + t] += val;
}

// ---------------- orchestration ----------------
extern "C" void kernel_launch(void* const* d_in, const int* in_sizes, int n_in,
                              void* d_out, int out_size, void* d_ws, size_t ws_size,
                              hipStream_t stream)
{
    const float* x_cnn   = (const float*)d_in[0];
    const int*   edge    = (const int*)d_in[1];
    const float* norm1_g = (const float*)d_in[2];
    const float* norm1_b = (const float*)d_in[3];
    const float* proj_w  = (const float*)d_in[4];
    const float* proj_b  = (const float*)d_in[5];
    const float* wq      = (const float*)d_in[6];
    const float* bq      = (const float*)d_in[7];
    const float* wk      = (const float*)d_in[8];
    const float* bk      = (const float*)d_in[9];
    const float* wv      = (const float*)d_in[10];
    const float* bv      = (const float*)d_in[11];
    const float* wo      = (const float*)d_in[12];
    const float* bo      = (const float*)d_in[13];
    const float* norm2_g = (const float*)d_in[14];
    const float* norm2_b = (const float*)d_in[15];
    const float* gpl_w   = (const float*)d_in[16];
    const float* gpl_b   = (const float*)d_in[17];
    const float* gat_w   = (const float*)d_in[18];
    const float* att_src = (const float*)d_in[19];
    const float* att_dst = (const float*)d_in[20];
    const float* gat_bias= (const float*)d_in[21];
    const float* norm3_g = (const float*)d_in[22];
    const float* norm3_b = (const float*)d_in[23];
    const float* mlp_w1  = (const float*)d_in[24];
    const float* mlp_b1  = (const float*)d_in[25];
    const float* mlp_w2  = (const float*)d_in[26];
    const float* mlp_b2  = (const float*)d_in[27];
    const float* fn_g    = (const float*)d_in[28];
    const float* fn_b    = (const float*)d_in[29];

    int Eed = in_sizes[1] / 2;
    float* out = (float*)d_out;

    const size_t NB = (size_t)NS * CH;   // 1,179,648
    float* ws   = (float*)d_ws;
    float* bufA = ws + 0 * NB;
    float* bufB = ws + 1 * NB;
    float* bufC = ws + 2 * NB;
    float* bufD = ws + 3 * NB;
    float* bufE = ws + 4 * NB;
    float* a_src = ws + 5 * NB;
    float* a_dst = a_src + NS;
    int*   deg   = (int*)(a_dst + NS);
    int*   csr   = deg + NS;             // NS*16 ints
    unsigned short* qb = (unsigned short*)(csr + (size_t)NS * 16);
    unsigned short* kb = qb + NB;
    unsigned short* vt = kb + NB;
    unsigned short* wt = vt + NB;        // 9 * 65536 bf16 transposed weights
    // total ws ≈ 33 MB

    // fold 1/sqrt(dh) AND log2(e) into q so softmax runs in exp2 domain
    const float qscale = 0.17677669529663687f * 1.4426950408889634f;
    dim3 gg(72, 8);       // 64x32 tiles over 4608x256
    dim3 gw(8, 8, 9);

    // 0. transpose+convert all weights to bf16 [n][k]
    k_wprep<<<gw, 256, 0, stream>>>(proj_w, wq, wk, wv, wo, gpl_w, gat_w,
                                    mlp_w1, mlp_w2, wt);
    // 1. tokenize + LN1 -> bufA
    k_ln_tok<<<NS, 256, 0, stream>>>(x_cnn, norm1_g, norm1_b, bufA);
    // 2. xv = bufA @ proj + proj_b -> bufB (fp32)
    k_gemm2<0,0,0><<<gg, 256, 0, stream>>>(bufA, wt + 0 * 65536, nullptr, nullptr,
                                           proj_b, nullptr, bufB, nullptr);
    // 3. fused q,k,v -> qb (scaled), kb, vt
    k_gemm_qkv<<<dim3(72, 8, 3), 256, 0, stream>>>(bufB, wt + 1 * 65536,
                                                   bq, bk, bv, qb, kb, vt, qscale);
    // 4. MFMA flash attention (32 q/block) -> bufA
    k_attn_mfma<<<dim3(72, 16), 256, 0, stream>>>(qb, kb, vt, bufA);
    // 5. nf = bufB + bufA @ wo + bo  (in-place into bufB)
    k_gemm2<0,0,0><<<gg, 256, 0, stream>>>(bufA, wt + 4 * 65536, nullptr, nullptr,
                                           bo, bufB, bufB, nullptr);
    // 6+7. xg = LN2(bufB) @ gpl_w + gpl_b -> bufD   (LN fused into GEMM prologue)
    k_gemm2<1,0,0><<<gg, 256, 0, stream>>>(bufB, wt + 5 * 65536, norm2_g, norm2_b,
                                           gpl_b, nullptr, bufD, nullptr);
    // 8. h = bufD @ gat_w -> bufE
    k_gemm2<0,0,0><<<gg, 256, 0, stream>>>(bufD, wt + 6 * 65536, nullptr, nullptr,
                                           nullptr, nullptr, bufE, nullptr);
    // 9. a_src/a_dst
    k_attvec<<<NS, 256, 0, stream>>>(bufE, att_src, att_dst, a_src, a_dst);
    // 10. CSR build
    (void)hipMemsetAsync(deg, 0, NS * sizeof(int), stream);
    k_fill_edges<<<(Eed + 255) / 256, 256, 0, stream>>>(edge, Eed, deg, csr);
    // 11. GAT aggregate + elu + residual (bufB updated in place)
    k_gat_agg<<<NS, 256, 0, stream>>>(deg, csr, a_src, a_dst, bufE, gat_bias, bufB);
    // 12+13. mlp1 = gelu(LN3(bufB) @ mlp_w1 + b1) -> bufD; xn -> bufC (WX, bn==0)
    k_gemm2<1,1,1><<<gg, 256, 0, stream>>>(bufB, wt + 7 * 65536, norm3_g, norm3_b,
                                           mlp_b1, nullptr, bufD, bufC);
    // 14. y_pre = bufC + bufD @ mlp_w2 + b2 -> bufA
    k_gemm2<0,0,0><<<gg, 256, 0, stream>>>(bufD, wt + 8 * 65536, nullptr, nullptr,
                                           mlp_b2, bufC, bufA, nullptr);
    // 15. final LN + transpose -> out
    k_ln_out<<<NS, 256, 0, stream>>>(bufA, fn_g, fn_b, out);
}